// Round 4
// baseline (148.031 us; speedup 1.0000x reference)
//
#include <hip/hip_runtime.h>

// SSIM (win=11, sigma=1.5, range=255), N=16 C=3 512x512 fp32 -> [16,502,502].
// R10: phase-split H/V + continuous 6-iteration stream.
// Evidence through R9: R9 == R6 bit-identical (52.6us) despite removing 2M
// conflict cycles, prefetching 2/3 channel loads, and ping-pong buffers =>
// (a) bank conflicts are OFF the critical path, (b) load latency is OFF the
// critical path, (c) ping-pong did NOT de-serialize q-chains because program
// order still interleaves H(q)->V(q)->H(q+1) and the scheduler won't hoist
// 60-instruction spans. The duration is the 15 serial per-channel
// MFMA->cvt->ds_write->lgkm->ds_read->MFMA round trips. R7 had the right fix
// (phase-split) but was confounded by its VGPR-64 spill.
// This round:
//  1. Phase-split: all 15 H-MFMAs+writes into per-q buffers s_ht[5][64][56]
//     (35.8KB), THEN all V-reads (b-major). One RAW exposure per channel
//     instead of five; writes pipeline back-to-back, reads drain behind them.
//     launch_bounds(256,2): VGPR free (~110 expected), no R7 spill.
//     Tripwire: WRITE_SIZE > 25MB = spill = this config is invalid.
//  2. Merged 6-iteration stream: each block does 2 row-tiles x 3 channels
//     (grid 8x8x16 = 1024, 4 blocks/CU matching the 4-block LDS limit),
//     prefetching the next iteration's 12 dwordx4 loads every iteration.
//     Loads continuously in flight; per-block fixed overhead halved.
// Per-output arithmetic and channel sum order identical to R6/R9 -> absmax
// must stay 0.0078125.
//
// Edge clamps: same proof as R6-R9. Staged row r feeds outrow nn iff
// 0<=r-nn<=10; clamped/duplicate rows feed only zero band-weights or outputs
// masked at the store. Tile1 (rowB+32) is the same proof with row0=rowB+32.
// HPITCH=56 (28 dw): H ds_write_b64 4 acc/bank, V ds_read_b128 8 acc/bank --
// structural minimum (verified R7-R9, conflicts 4.42M->2.46M).
//
// MFMA scheme (mfma_f32_16x16x32_f16), B[k][n] = W[k-n] banded, both passes:
//  H: A[m=row][k=col] -> D[m=row][n=outcol]; C-layout (col=lane&15,
//     row=(lane>>4)*4+reg) -> ds_write_b64 transposed into H_T[outcol][row].
//  V: A[m=outcol][k=row] from H_T (k contiguous -> ds_read_b128),
//     D[m=outcol][n=outrow]. Wave owns a 16-outcol chunk for both passes.

namespace {

constexpr int NN = 16, CC = 3, HH = 512, WW = 512;
constexpr int OH = HH - 10, OW = WW - 10;          // 502 x 502
constexpr int TW = 64, TH = 32, RT = 2;            // 64x32 tile, 2 tiles/block
constexpr int HP = 56;                             // H_T row pitch (f16)
constexpr float C1c = 6.5025f;                     // (0.01*255)^2
constexpr float C2c = 58.5225f;                    // (0.03*255)^2

typedef _Float16 half8   __attribute__((ext_vector_type(8)));
typedef _Float16 half4   __attribute__((ext_vector_type(4)));
typedef float    floatv4 __attribute__((ext_vector_type(4)));

__device__ const float WF[11] = {
    0.00102838f, 0.00759876f, 0.03600077f, 0.10936069f, 0.21300553f,
    0.26601172f,
    0.21300553f, 0.10936069f, 0.03600077f, 0.00759876f, 0.00102838f
};

__device__ inline half8 pack8(const float4& a, const float4& b) {
    half8 h = {(_Float16)a.x, (_Float16)a.y, (_Float16)a.z, (_Float16)a.w,
               (_Float16)b.x, (_Float16)b.y, (_Float16)b.z, (_Float16)b.w};
    return h;
}

__global__ __launch_bounds__(256, 2)
void ssim_kernel(const float* __restrict__ X, const float* __restrict__ Y,
                 float* __restrict__ out)
{
    // per-quantity transpose buffers: 5*64*56*2 = 35840 B (4 blocks/CU)
    __shared__ __align__(16) _Float16 s_ht[5][TW][HP];
    __shared__ _Float16 s_wtab[16];

    const int tid  = threadIdx.x;
    const int lane = tid & 63;
    const int wv   = tid >> 6;          // wave id = outcol chunk (16 cols)
    const int col0 = blockIdx.x * TW;
    const int rowB = blockIdx.y * (TH * RT);
    const int n    = blockIdx.z;

    if (tid < 16) s_wtab[tid] = (tid < 11) ? (_Float16)WF[tid] : (_Float16)0.f;
    __syncthreads();   // only block-wide sync in the kernel

    // banded weight fragment B[k][n] = W[k-n]; lane: n=lane&15, k=(lane>>4)*8+j
    half8 bfrag;
    {
        const int bn = lane & 15, kq = (lane >> 4) * 8;
        #pragma unroll
        for (int j = 0; j < 8; ++j) {
            int kk = kq + j - bn;
            kk = (kk < 0 || kk > 10) ? 11 : kk;   // index 11 holds 0
            bfrag[j] = s_wtab[kk];
        }
    }

    const int arow = lane & 15;          // A m-row select / V outrow-local
    const int aq   = lane >> 4;          // A k-quad
    const int crow = aq * 4;             // C-layout row base

    // per-lane load offsets for both row-tiles (uniform clamps; clamped
    // lanes feed only zero-weight taps or store-masked outputs)
    int gcol = col0 + wv * 16 + aq * 8;
    gcol = gcol <= WW - 8 ? gcol : WW - 8;         // stays 32B-aligned
    int voffs[RT][3];
    #pragma unroll
    for (int t = 0; t < RT; ++t) {
        #pragma unroll
        for (int rc = 0; rc < 3; ++rc) {
            int g = rowB + t * TH + rc * 16 + arow;
            g = g < HH ? g : HH - 1;
            voffs[t][rc] = g * WW + gcol;
        }
    }

    const size_t plane = (size_t)HH * WW;
    const float* Xn = X + (size_t)n * CC * plane;
    const float* Yn = Y + (size_t)n * CC * plane;
    const floatv4 zf = {0.f, 0.f, 0.f, 0.f};

    // ---- prologue: issue (t=0, ch=0)'s 12 independent dwordx4 loads ----
    float4 fx[3][2], fy[3][2];
    #pragma unroll
    for (int rc = 0; rc < 3; ++rc) {
        const float* bx = Xn + voffs[0][rc];
        const float* by = Yn + voffs[0][rc];
        fx[rc][0] = *(const float4*)bx;
        fx[rc][1] = *(const float4*)(bx + 4);
        fy[rc][0] = *(const float4*)by;
        fy[rc][1] = *(const float4*)(by + 4);
    }

    float acc[2][4] = {{0.f,0.f,0.f,0.f},{0.f,0.f,0.f,0.f}};

    #pragma unroll
    for (int t = 0; t < RT; ++t) {
        #pragma unroll
        for (int ch = 0; ch < CC; ++ch) {
            // consume fx/fy into f16 packs (frees them as prefetch targets)
            half8 axf[3], ayf[3];
            #pragma unroll
            for (int rc = 0; rc < 3; ++rc) {
                axf[rc] = pack8(fx[rc][0], fx[rc][1]);
                ayf[rc] = pack8(fy[rc][0], fy[rc][1]);
            }

            // ---- prefetch next iteration's loads (uniform branch) ----
            const int nch = (ch == CC - 1) ? 0 : ch + 1;
            const int nt  = (ch == CC - 1) ? t + 1 : t;
            if (nt < RT) {
                const float* Xc = Xn + (size_t)nch * plane;
                const float* Yc = Yn + (size_t)nch * plane;
                #pragma unroll
                for (int rc = 0; rc < 3; ++rc) {
                    const float* bx = Xc + voffs[nt][rc];
                    const float* by = Yc + voffs[nt][rc];
                    fx[rc][0] = *(const float4*)bx;
                    fx[rc][1] = *(const float4*)(bx + 4);
                    fy[rc][0] = *(const float4*)by;
                    fy[rc][1] = *(const float4*)(by + 4);
                }
            }

            // ---- Phase H: all 15 H-MFMAs -> cvt -> ds_write, per-q
            // buffers, zero RAW between them ----
            #pragma unroll
            for (int qi = 0; qi < 5; ++qi) {
                #pragma unroll
                for (int rc = 0; rc < 3; ++rc) {
                    half8 a;
                    if      (qi == 0) a = axf[rc];             // x
                    else if (qi == 1) a = ayf[rc];             // y
                    else if (qi == 2) a = axf[rc] * axf[rc];   // xx
                    else if (qi == 3) a = ayf[rc] * ayf[rc];   // yy
                    else              a = axf[rc] * ayf[rc];   // xy
                    floatv4 d = __builtin_amdgcn_mfma_f32_16x16x32_f16(
                        a, bfrag, zf, 0, 0, 0);
                    half4 h = {(_Float16)d[0], (_Float16)d[1],
                               (_Float16)d[2], (_Float16)d[3]};
                    *(half4*)&s_ht[qi][wv*16 + arow][rc*16 + crow] = h;
                }
            }

            // ---- Phase V + SSIM, b-major (5 V-frags live at once).
            // Per-wave DS in-order: reads execute after the writes above;
            // fine-grained lgkmcnt lets reads drain behind the write queue.
            #pragma unroll
            for (int b = 0; b < 2; ++b) {
                floatv4 v[5];
                #pragma unroll
                for (int qi = 0; qi < 5; ++qi) {
                    half8 av = *(const half8*)
                        &s_ht[qi][wv*16 + arow][b*16 + aq*8];
                    v[qi] = __builtin_amdgcn_mfma_f32_16x16x32_f16(
                        av, bfrag, zf, 0, 0, 0);
                }
                #pragma unroll
                for (int p = 0; p < 4; ++p) {
                    float m1 = v[0][p], m2 = v[1][p];
                    float exx = v[2][p], eyy = v[3][p], exy = v[4][p];
                    float m1s = m1*m1, m2s = m2*m2, m12 = m1*m2;
                    float s1 = exx - m1s, s2 = eyy - m2s, s12 = exy - m12;
                    float n1 = 2.f*m12 + C1c, d1 = m1s + m2s + C1c;
                    float n2 = 2.f*s12 + C2c, d2 = s1 + s2 + C2c;
                    acc[b][p] = fmaf(n1 * n2,
                                     __builtin_amdgcn_rcpf(d1 * d2),
                                     acc[b][p]);
                }
            }
        }

        // ---- epilogue for tile t: 1 - mean over channels ----
        #pragma unroll
        for (int b = 0; b < 2; ++b) {
            const int orow = rowB + t * TH + b * 16 + arow;
            const int ocol = col0 + wv * 16 + crow;
            if (orow < OH) {
                float r0v = 1.f - acc[b][0] * (1.f/3.f);
                float r1v = 1.f - acc[b][1] * (1.f/3.f);
                float r2v = 1.f - acc[b][2] * (1.f/3.f);
                float r3v = 1.f - acc[b][3] * (1.f/3.f);
                size_t base = ((size_t)n * OH + orow) * OW + ocol;
                if (ocol + 3 < OW) {
                    *(float2*)(out + base)     = make_float2(r0v, r1v);
                    *(float2*)(out + base + 2) = make_float2(r2v, r3v);
                } else {
                    float rs[4] = {r0v, r1v, r2v, r3v};
                    #pragma unroll
                    for (int p = 0; p < 4; ++p)
                        if (ocol + p < OW) out[base + p] = rs[p];
                }
            }
            // reset for next tile
            acc[b][0] = acc[b][1] = acc[b][2] = acc[b][3] = 0.f;
        }
    }
}

} // namespace

extern "C" void kernel_launch(void* const* d_in, const int* in_sizes, int n_in,
                              void* d_out, int out_size, void* d_ws, size_t ws_size,
                              hipStream_t stream) {
    const float* X = (const float*)d_in[0];
    const float* Y = (const float*)d_in[1];
    float* out = (float*)d_out;

    dim3 grid((OW + TW - 1) / TW,             // 8
              (OH + TH * RT - 1) / (TH * RT), // 8
              NN);                            // 16
    ssim_kernel<<<grid, 256, 0, stream>>>(X, Y, out);
}

// Round 5
// 133.996 us; speedup vs baseline: 1.1047x; 1.1047x over previous
//
#include <hip/hip_runtime.h>

// SSIM (win=11, sigma=1.5, range=255), N=16 C=3 512x512 fp32 -> [16,502,502].
// R11: cooperative double-buffered global_load_lds staging + R9 compute core.
// Evidence R6-R10: duration ~= hbm-visible traffic / ~1.7-2.0 TB/s in EVERY
// structural variant; logical read volume (12KB per wave-channel, direct
// per-wave global dwordx4) was the cross-round invariant. Conflicts, RAW
// round-trips, load prefetch, occupancy all falsified as levers. The one
// untried canonical pattern: stage the block's input tile ONCE (30KB vs 48KB
// per block-channel), direct-to-LDS (no VGPR round trip, no per-lane 64-bit
// addr math x36), double-buffered so HBM latency hides under compute.
// R3-R5's staging failed due to __syncthreads' full vmcnt(0) drain + no
// double buffer; here: raw s_barrier + per-wave COUNTED vmcnt (ledger below).
//
// Staging ledger (per wave; vm ops = its own 8 (wv<3) / 6 (wv==3) stages):
//   prologue: STAGE(ch0->buf0), STAGE(ch1->buf1)     pending 16|12
//   ch0: wait vmcnt(8|6)  -> STAGE0 done (STAGE1 in flight) ... barrier
//        reads buf0 ... lgkmcnt(0) ... barrier ... STAGE(ch2->buf0)
//   ch1: wait vmcnt(8|6)  -> STAGE1 done (STAGE2 in flight)
//   ch2: wait vmcnt(0)    -> STAGE2 done
// Each wave waits its own count before barrier => after barrier ALL stages
// of that buffer are complete. lgkmcnt(0)+barrier before re-staging buf0
// guarantees no wave still reads it. sched_barrier(0) fences pin ordering.
//
// Staged tile: rows 48 x cols 80 f32 per input (row/col clamped; clamped
// data feeds only zero band-weights or store-masked outputs -- same proof
// as R6-R10; staged row r feeds outrow nn iff 0<=r-nn<=10; staged col rel
// >=64 only feeds out cols >=502 which are masked).
// Chunk map: c in [0,960): row=c/20, col4=c%20; wave w stages chunks
// (w*4+i)*64+lane, i<4 (w<3) / i<3 (w==3): all-full-lane wave instrs.
//
// Compute core IDENTICAL to R9 (proven == R6 bit-exact, 52.6us):
// mfma_f32_16x16x32_f16, B[k][n]=W[k-n] banded, H->s_ht transpose
// (HPITCH=56, ping-pong [qi&1]) -> V -> SSIM. q order {xy,xx,x,yy,y}.
// absmax must stay 0.0078125.

namespace {

constexpr int NN = 16, CC = 3, HH = 512, WW = 512;
constexpr int OH = HH - 10, OW = WW - 10;          // 502 x 502
constexpr int TW = 64, TH = 32;                    // output tile per block
constexpr int SROWS = 48, SCOLS = 80;              // staged tile (f32)
constexpr int SCH = SROWS * SCOLS;                 // 3840 f32 = 15360 B
constexpr int HPITCH = 56;                         // H_T row pitch (f16)
constexpr float C1c = 6.5025f;                     // (0.01*255)^2
constexpr float C2c = 58.5225f;                    // (0.03*255)^2

// s_waitcnt imms: vmcnt-only waits keep expcnt=7, lgkmcnt=15 (no wait).
constexpr int WC_VM8 = 0xF78;    // vmcnt(8)
constexpr int WC_VM6 = 0xF76;    // vmcnt(6)
constexpr int WC_VM0 = 0xF70;    // vmcnt(0)
constexpr int WC_LG0 = 0xC07F;   // lgkmcnt(0) only (vmcnt=63, expcnt=7)

typedef _Float16 half8   __attribute__((ext_vector_type(8)));
typedef _Float16 half4   __attribute__((ext_vector_type(4)));
typedef float    floatv4 __attribute__((ext_vector_type(4)));
typedef unsigned int u32;
typedef u32 __attribute__((address_space(1))) gu32;
typedef u32 __attribute__((address_space(3))) lu32;

__device__ const float WF[11] = {
    0.00102838f, 0.00759876f, 0.03600077f, 0.10936069f, 0.21300553f,
    0.26601172f,
    0.21300553f, 0.10936069f, 0.03600077f, 0.00759876f, 0.00102838f
};

__device__ inline half8 pack8(const float4& a, const float4& b) {
    half8 h = {(_Float16)a.x, (_Float16)a.y, (_Float16)a.z, (_Float16)a.w,
               (_Float16)b.x, (_Float16)b.y, (_Float16)b.z, (_Float16)b.w};
    return h;
}

__device__ inline void stage16(const float* g, void* l) {
    __builtin_amdgcn_global_load_lds((const gu32*)g, (lu32*)l, 16, 0, 0);
}

__global__ __launch_bounds__(256, 2)
void ssim_kernel(const float* __restrict__ X, const float* __restrict__ Y,
                 float* __restrict__ out)
{
    // staged input: [buf][x/y][48*80] f32 = 61440 B
    __shared__ __align__(16) float s_in[2][2][SCH];
    // transpose ping-pong: 2*64*56*2 = 14336 B
    __shared__ __align__(16) _Float16 s_ht[2][TW][HPITCH];
    __shared__ _Float16 s_wtab[16];

    const int tid  = threadIdx.x;
    const int lane = tid & 63;
    const int wv   = tid >> 6;          // wave id = outcol chunk (16 cols)
    const int col0 = blockIdx.x * TW;
    const int row0 = blockIdx.y * TH;
    const int n    = blockIdx.z;

    if (tid < 16) s_wtab[tid] = (tid < 11) ? (_Float16)WF[tid] : (_Float16)0.f;
    __syncthreads();

    // banded weight fragment B[k][n] = W[k-n]; lane: n=lane&15, k=(lane>>4)*8+j
    half8 bfrag;
    {
        const int bn = lane & 15, kq = (lane >> 4) * 8;
        #pragma unroll
        for (int j = 0; j < 8; ++j) {
            int kk = kq + j - bn;
            kk = (kk < 0 || kk > 10) ? 11 : kk;   // index 11 holds 0
            bfrag[j] = s_wtab[kk];
        }
    }

    const int arow = lane & 15;          // A m-row select / V outrow-local
    const int aq   = lane >> 4;          // A k-quad
    const int crow = aq * 4;             // C-layout row base

    // per-lane staging source offsets (channel-invariant; clamped)
    int sOff[4];
    const int sCnt = (wv < 3) ? 4 : 3;
    #pragma unroll
    for (int i = 0; i < 4; ++i) {
        const int c  = (wv * 4 + i) * 64 + lane;  // chunk id
        const int r  = c / 20;
        const int c4 = c - r * 20;
        int gr = row0 + r;        gr = gr < HH ? gr : HH - 1;
        int gc = col0 + c4 * 4;   gc = gc <= WW - 4 ? gc : WW - 4;
        sOff[i] = gr * WW + gc;
    }

    const size_t plane = (size_t)HH * WW;
    const float* Xn = X + (size_t)n * CC * plane;
    const float* Yn = Y + (size_t)n * CC * plane;

    auto STAGE = [&](int nc, int b) {
        const float* Xc = Xn + (size_t)nc * plane;
        const float* Yc = Yn + (size_t)nc * plane;
        #pragma unroll
        for (int i = 0; i < 4; ++i) {
            if (i < sCnt) {   // wave-uniform
                char* lx = (char*)&s_in[b][0][0] + (wv * 4 + i) * 1024;
                char* ly = (char*)&s_in[b][1][0] + (wv * 4 + i) * 1024;
                stage16(Xc + sOff[i], lx);
                stage16(Yc + sOff[i], ly);
            }
        }
    };

    // ---- prologue: stage ch0 and ch1 ----
    STAGE(0, 0);
    STAGE(1, 1);

    float acc[2][4] = {{0.f,0.f,0.f,0.f},{0.f,0.f,0.f,0.f}};
    const floatv4 zf = {0.f, 0.f, 0.f, 0.f};
    const int cbase = wv * 16 + aq * 8;   // fragment col base (rel)

    for (int ch = 0; ch < CC; ++ch) {
        const int b = ch & 1;             // 0,1,0

        // wait: current buffer fully staged (own stages; barrier joins all)
        if (ch < 2) {
            if (wv < 3) __builtin_amdgcn_s_waitcnt(WC_VM8);
            else        __builtin_amdgcn_s_waitcnt(WC_VM6);
        } else {
            __builtin_amdgcn_s_waitcnt(WC_VM0);
        }
        __builtin_amdgcn_sched_barrier(0);
        __builtin_amdgcn_s_barrier();
        __builtin_amdgcn_sched_barrier(0);

        // ---- fragment reads from staged tile (12x ds_read_b128) ----
        half8 axf[3], ayf[3];
        #pragma unroll
        for (int rc = 0; rc < 3; ++rc) {
            const int idx = (rc * 16 + arow) * SCOLS + cbase;
            float4 a0 = *(const float4*)&s_in[b][0][idx];
            float4 a1 = *(const float4*)&s_in[b][0][idx + 4];
            float4 b0 = *(const float4*)&s_in[b][1][idx];
            float4 b1 = *(const float4*)&s_in[b][1][idx + 4];
            axf[rc] = pack8(a0, a1);
            ayf[rc] = pack8(b0, b1);
        }
        __builtin_amdgcn_s_waitcnt(WC_LG0);   // reads retired before re-stage
        __builtin_amdgcn_sched_barrier(0);
        __builtin_amdgcn_s_barrier();
        __builtin_amdgcn_sched_barrier(0);

        if (ch == 0) STAGE(2, 0);   // buf0 free now; hides under compute

        // ---- H + V MFMA per quantity, ping-pong s_ht[qi&1] (R9 core).
        // q order {xy,xx,x,yy,y}: axf dead after qi==2. ----
        floatv4 vfr[5][2];
        #pragma unroll
        for (int qi = 0; qi < 5; ++qi) {
            #pragma unroll
            for (int rc = 0; rc < 3; ++rc) {
                half8 a;
                if      (qi == 0) a = axf[rc] * ayf[rc];   // xy
                else if (qi == 1) a = axf[rc] * axf[rc];   // xx
                else if (qi == 2) a = axf[rc];             // x (last axf use)
                else if (qi == 3) a = ayf[rc] * ayf[rc];   // yy
                else              a = ayf[rc];             // y
                floatv4 d = __builtin_amdgcn_mfma_f32_16x16x32_f16(
                    a, bfrag, zf, 0, 0, 0);
                half4 h = {(_Float16)d[0], (_Float16)d[1],
                           (_Float16)d[2], (_Float16)d[3]};
                *(half4*)&s_ht[qi & 1][wv*16 + arow][rc*16 + crow] = h;
            }
            #pragma unroll
            for (int bb = 0; bb < 2; ++bb) {
                half8 av = *(const half8*)
                    &s_ht[qi & 1][wv*16 + arow][bb*16 + aq*8];
                vfr[qi][bb] = __builtin_amdgcn_mfma_f32_16x16x32_f16(
                    av, bfrag, zf, 0, 0, 0);
            }
        }

        // ---- SSIM on V fragments (vfr: 0=xy 1=xx 2=x 3=yy 4=y) ----
        #pragma unroll
        for (int bb = 0; bb < 2; ++bb) {
            #pragma unroll
            for (int p = 0; p < 4; ++p) {
                float m1 = vfr[2][bb][p], m2 = vfr[4][bb][p];
                float exx = vfr[1][bb][p], eyy = vfr[3][bb][p],
                      exy = vfr[0][bb][p];
                float m1s = m1*m1, m2s = m2*m2, m12 = m1*m2;
                float s1 = exx - m1s, s2 = eyy - m2s, s12 = exy - m12;
                float n1 = 2.f*m12 + C1c, d1 = m1s + m2s + C1c;
                float n2 = 2.f*s12 + C2c, d2 = s1 + s2 + C2c;
                acc[bb][p] = fmaf(n1 * n2, __builtin_amdgcn_rcpf(d1 * d2),
                                  acc[bb][p]);
            }
        }
    }

    // ---- epilogue: 1 - mean over channels ----
    #pragma unroll
    for (int bb = 0; bb < 2; ++bb) {
        const int orow = row0 + bb*16 + arow;
        const int ocol = col0 + wv*16 + crow;
        if (orow < OH) {
            float r0v = 1.f - acc[bb][0] * (1.f/3.f);
            float r1v = 1.f - acc[bb][1] * (1.f/3.f);
            float r2v = 1.f - acc[bb][2] * (1.f/3.f);
            float r3v = 1.f - acc[bb][3] * (1.f/3.f);
            size_t base = ((size_t)n * OH + orow) * OW + ocol;
            if (ocol + 3 < OW) {
                *(float2*)(out + base)     = make_float2(r0v, r1v);
                *(float2*)(out + base + 2) = make_float2(r2v, r3v);
            } else {
                float rs[4] = {r0v, r1v, r2v, r3v};
                #pragma unroll
                for (int p = 0; p < 4; ++p)
                    if (ocol + p < OW) out[base + p] = rs[p];
            }
        }
    }
}

} // namespace

extern "C" void kernel_launch(void* const* d_in, const int* in_sizes, int n_in,
                              void* d_out, int out_size, void* d_ws, size_t ws_size,
                              hipStream_t stream) {
    const float* X = (const float*)d_in[0];
    const float* Y = (const float*)d_in[1];
    float* out = (float*)d_out;

    dim3 grid((OW + TW - 1) / TW,   // 8
              (OH + TH - 1) / TH,   // 16
              NN);                  // 16
    ssim_kernel<<<grid, 256, 0, stream>>>(X, Y, out);
}